// Round 1
// baseline (464.956 us; speedup 1.0000x reference)
//
#include <hip/hip_runtime.h>

// NeRF volume rendering: one lane per sample, 32 lanes per ray (2 rays/wave).
// pred float4 loads are perfectly coalesced (flat index == gid).
// Exclusive cumprod via shfl_up multiply-scan; rgb/depth via shfl_down reduce.

__global__ __launch_bounds__(256) void nerf_render_kernel(
    const float4* __restrict__ pred4,   // [rays*32] float4 (rgb logits + sigma)
    const float*  __restrict__ tvals,   // [rays*32]
    float* __restrict__ out_rgb,        // [rays*3]
    float* __restrict__ out_depth,      // [rays]
    int total_samples)
{
    const int gid = blockIdx.x * 256 + threadIdx.x;
    if (gid >= total_samples) return;            // total_samples % 32 == 0, so
    const int lane = threadIdx.x & 31;           // 32-lane segments stay intact
    const int ray  = gid >> 5;

    const float4 p  = pred4[gid];
    const float  tv = tvals[gid];

    // delta[i] = t[i+1] - t[i], last = 1e10
    const float tn    = __shfl_down(tv, 1, 32);
    const float delta = (lane == 31) ? 1e10f : (tn - tv);

    const float sigma = fmaxf(p.w, 0.0f);
    const float et    = __expf(-sigma * delta);  // exp_term = 1 - alpha
    const float alpha = 1.0f - et;
    const float ep    = et + 1e-10f;

    // inclusive product-scan over the 32-lane segment
    float v = ep;
    #pragma unroll
    for (int off = 1; off < 32; off <<= 1) {
        const float t = __shfl_up(v, off, 32);
        v = (lane >= off) ? v * t : v;
    }
    // exclusive: transmittance[i] = prod_{k<i} ep[k]
    float T = __shfl_up(v, 1, 32);
    T = (lane == 0) ? 1.0f : T;

    const float w = alpha * T;
    float r = w / (1.0f + __expf(-p.x));
    float g = w / (1.0f + __expf(-p.y));
    float b = w / (1.0f + __expf(-p.z));
    float d = w * tv;

    // tree-reduce within the 32-lane segment (lane 0 ends with the sum)
    #pragma unroll
    for (int off = 16; off >= 1; off >>= 1) {
        r += __shfl_down(r, off, 32);
        g += __shfl_down(g, off, 32);
        b += __shfl_down(b, off, 32);
        d += __shfl_down(d, off, 32);
    }

    if (lane == 0) {
        out_rgb[ray * 3 + 0] = r;
        out_rgb[ray * 3 + 1] = g;
        out_rgb[ray * 3 + 2] = b;
        out_depth[ray]       = d;
    }
}

extern "C" void kernel_launch(void* const* d_in, const int* in_sizes, int n_in,
                              void* d_out, int out_size, void* d_ws, size_t ws_size,
                              hipStream_t stream) {
    const float4* pred4 = (const float4*)d_in[0];     // [B,H,W,32,4] f32
    const float*  tvals = (const float*)d_in[1];      // [B,H,W,32]   f32

    const int total_samples = in_sizes[1];            // B*H*W*32 = 20,480,000
    const int rays          = total_samples / 32;     // 640,000

    float* out_rgb   = (float*)d_out;                 // first rays*3 floats
    float* out_depth = (float*)d_out + (size_t)rays * 3;

    const int block = 256;
    const int grid  = (total_samples + block - 1) / block;
    nerf_render_kernel<<<grid, block, 0, stream>>>(pred4, tvals, out_rgb,
                                                   out_depth, total_samples);
}